// Round 8
// baseline (121.603 us; speedup 1.0000x reference)
//
#include <hip/hip_runtime.h>
#include <hip/hip_bf16.h>

#define B_ 2
#define H_ 16
#define S_ 2048
#define D_ 64

typedef __attribute__((ext_vector_type(8))) short bf16x8;
typedef __attribute__((ext_vector_type(8))) unsigned short u16x8;
typedef __attribute__((ext_vector_type(4))) unsigned int u32x4;
typedef __attribute__((ext_vector_type(4))) float f32x4;
typedef unsigned short ushort_t;

#define SCALE 0.18033688011112042f  // (1/sqrt(64)) * log2(e)

__device__ __forceinline__ unsigned short f2bf(float x) {
  unsigned int u = __builtin_bit_cast(unsigned int, x);
  unsigned int r = (u + 0x7FFFu + ((u >> 16) & 1u)) >> 16;
  return (unsigned short)r;
}

__device__ __forceinline__ unsigned int cvt_pk_bf16(float lo, float hi) {
  unsigned int r;
  asm("v_cvt_pk_bf16_f32 %0, %1, %2" : "=v"(r) : "v"(lo), "v"(hi));
  return r;
}

// raw v_exp_f32 (2^x). Safe here: x <= 8 always, x may be -inf -> 0.
__device__ __forceinline__ float fast_exp2(float x) {
  float r;
  asm("v_exp_f32 %0, %1" : "=v"(r) : "v"(x));
  return r;
}

__device__ __forceinline__ float fmax3(float a, float b, float c) {
  return fmaxf(fmaxf(a, b), c);  // clang fuses to v_max3_f32
}

// sigma: LDS row rl holds K row sigma(rl); bit permute (b5 b4 b3 b2 b1 b0) ->
// (b5 b3 b2 b4 b1 b0). Makes QK^T D-layout == PV B-frag order (P stays in reg).
__device__ __forceinline__ int sigma_row(int rl) {
  return (rl & 0x23) | ((rl & 0x0C) << 1) | ((rl & 0x10) >> 2);
}

#define GLL16(gp, lp)                                                          \
  __builtin_amdgcn_global_load_lds(                                            \
      (const __attribute__((address_space(1))) unsigned int*)(gp),             \
      (__attribute__((address_space(3))) unsigned int*)(lp), 16, 0, 0)

// ---------------- prepass: K/V fp32 -> bf16, swizzle + K-row-permute baked --
__global__ void prepack(const float* __restrict__ Kf, const float* __restrict__ Vf,
                        ushort_t* __restrict__ Kg, ushort_t* __restrict__ Vtg) {
  const int blk = blockIdx.x;  // bh*32 + t
  const int tid = threadIdx.x;
  const int bh = blk >> 5, t = blk & 31;
  const float* srcK = Kf + ((size_t)bh * S_ + (size_t)t * 64) * D_;
  const float* srcV = Vf + ((size_t)bh * S_ + (size_t)t * 64) * D_;
  ushort_t* dK = Kg + (size_t)blk * 4096;
  ushort_t* dV = Vtg + (size_t)blk * 4096;
  for (int is = 0; is < 2; ++is) {
    const int e = is * 2048 + tid * 8;
    {  // K with sigma row permute
      const int rl = e >> 6, pos = (e >> 3) & 7, ch = pos ^ (rl & 7);
      const float* sp = srcK + sigma_row(rl) * 64 + ch * 8;
      float4 a = *(const float4*)sp;
      float4 b = *(const float4*)(sp + 4);
      u16x8 w;
      w[0] = f2bf(a.x); w[1] = f2bf(a.y); w[2] = f2bf(a.z); w[3] = f2bf(a.w);
      w[4] = f2bf(b.x); w[5] = f2bf(b.y); w[6] = f2bf(b.z); w[7] = f2bf(b.w);
      *(u16x8*)(dK + e) = w;
    }
    {  // V transposed
      const int d0 = e >> 6, pos = (e >> 3) & 7, ch = pos ^ (d0 & 7);
      u16x8 w;
      for (int i = 0; i < 8; ++i) w[i] = f2bf(srcV[(size_t)(ch * 8 + i) * 64 + d0]);
      *(u16x8*)(dV + e) = w;
    }
  }
}

// ---------------- hot kernel: pipelined swapped-QK^T flash attention --------
// BODY(t): STAGE V(t+1),K(t+2); ds_read K(t+1)->kreg, V(t)->vreg;
//          SM(t) [VALU overlaps ds latency]; QK_MMA(t+1); PV(t) [pure reg];
//          barrier.
template <int PRE>
__launch_bounds__(256, 4)
__global__ void attn8(const float* __restrict__ Qf, const float* __restrict__ Kf,
                      const float* __restrict__ Vf, const ushort_t* __restrict__ Kg,
                      const ushort_t* __restrict__ Vtg, float* __restrict__ O) {
  const int bh = blockIdx.x;          // 0..31
  const int qt = 31 - blockIdx.y;     // LPT: longest blocks first
  const int tid = threadIdx.x;
  const int wave = tid >> 6, lane = tid & 63;
  const int col = lane & 15, g = lane >> 4;

  __shared__ __align__(16) ushort_t Kl[3][64][64];  // 24576 B (triple buf)
  __shared__ __align__(16) ushort_t Vt[2][64][64];  // 16384 B (double buf)

  float* Oh = O + (size_t)bh * S_ * D_;

  // ---- Q fragment (one-time): lane holds Q[qrow][32kk+8g+i] ----
  const int qrow = qt * 64 + wave * 16 + col;
  bf16x8 qf[2];
  {
    const float* Qh = Qf + (size_t)bh * S_ * D_;
    for (int kk = 0; kk < 2; ++kk) {
      const float* p = Qh + (size_t)qrow * 64 + kk * 32 + g * 8;
      float4 a = *(const float4*)p;
      float4 b = *(const float4*)(p + 4);
      float v[8] = {a.x, a.y, a.z, a.w, b.x, b.y, b.z, b.w};
      bf16x8 w;
      for (int i = 0; i < 8; ++i) w[i] = (short)f2bf(v[i] * SCALE);
      qf[kk] = w;
    }
  }

  f32x4 acc[4] = {};
  float m_ = -INFINITY, l_ = 0.0f;  // l_ per-lane partial (combined at end)

  const int ch0 = (g ^ (col & 7)) << 3;
  const int ch1 = ((4 | g) ^ (col & 7)) << 3;

  auto STAGE_K = [&](int t, int kb) {
    if (PRE) {
      const ushort_t* kg = Kg + ((size_t)(bh * 32 + t)) * 4096;
      GLL16(kg + tid * 8,        &Kl[kb][0][0] + tid * 8);
      GLL16(kg + 2048 + tid * 8, &Kl[kb][0][0] + 2048 + tid * 8);
    } else {
      const float* Kh = Kf + (size_t)bh * S_ * D_;
      const int rl = tid >> 2;
      const int c0 = (tid & 3) << 4;
      const float* src = Kh + ((size_t)(t * 64 + sigma_row(rl))) * 64 + c0;
      for (int jj = 0; jj < 2; ++jj) {
        float4 x = *(const float4*)(src + jj * 8);
        float4 y = *(const float4*)(src + jj * 8 + 4);
        u16x8 w;
        w[0] = f2bf(x.x); w[1] = f2bf(x.y); w[2] = f2bf(x.z); w[3] = f2bf(x.w);
        w[4] = f2bf(y.x); w[5] = f2bf(y.y); w[6] = f2bf(y.z); w[7] = f2bf(y.w);
        const int ch = (c0 >> 3) + jj;
        *(u16x8*)&Kl[kb][rl][(ch ^ (rl & 7)) << 3] = w;
      }
    }
  };
  auto STAGE_V = [&](int t, int vb) {
    if (PRE) {
      const ushort_t* vg = Vtg + ((size_t)(bh * 32 + t)) * 4096;
      GLL16(vg + tid * 8,        &Vt[vb][0][0] + tid * 8);
      GLL16(vg + 2048 + tid * 8, &Vt[vb][0][0] + 2048 + tid * 8);
    } else {
      const float* Vh = Vf + (size_t)bh * S_ * D_;
      const int c = tid & 63;
      const int r0 = (tid >> 6) << 4;
      const float* src = Vh + ((size_t)(t * 64 + r0)) * 64 + c;
      for (int jj = 0; jj < 2; ++jj) {
        u16x8 w;
        for (int i = 0; i < 8; ++i) w[i] = f2bf(src[(size_t)(jj * 8 + i) * 64]);
        const int ch = (r0 >> 3) + jj;
        *(u16x8*)&Vt[vb][c][(ch ^ (c & 7)) << 3] = w;
      }
    }
  };

  bf16x8 kreg[8], vreg[8];
  auto QK_LOAD = [&](int kb) {
    #pragma unroll
    for (int nt = 0; nt < 4; ++nt) {
      const ushort_t* row = &Kl[kb][nt * 16 + col][0];
      kreg[2 * nt]     = *(const bf16x8*)(row + ch0);
      kreg[2 * nt + 1] = *(const bf16x8*)(row + ch1);
    }
  };
  auto V_LOAD = [&](int vb) {
    #pragma unroll
    for (int nt = 0; nt < 4; ++nt) {
      const ushort_t* row = &Vt[vb][nt * 16 + col][0];
      vreg[2 * nt]     = *(const bf16x8*)(row + ch0);
      vreg[2 * nt + 1] = *(const bf16x8*)(row + ch1);
    }
  };
  auto QK_MMA = [&](f32x4 (&sn)[4]) {
    __builtin_amdgcn_s_setprio(1);
    #pragma unroll
    for (int nt = 0; nt < 4; ++nt) {
      f32x4 z = {0.f, 0.f, 0.f, 0.f};
      z = __builtin_amdgcn_mfma_f32_16x16x32_bf16(kreg[2 * nt], qf[0], z, 0, 0, 0);
      sn[nt] = __builtin_amdgcn_mfma_f32_16x16x32_bf16(kreg[2 * nt + 1], qf[1], z, 0, 0, 0);
    }
    __builtin_amdgcn_s_setprio(0);
  };

  auto SM = [&](f32x4 (&s)[4], bool diag, bf16x8& pf0, bf16x8& pf1) {
    if (diag) {
      const int qloc = wave * 16 + col;
      #pragma unroll
      for (int nt = 0; nt < 4; ++nt) {
        const int tau_base = 32 * (nt >> 1) + 4 * (nt & 1) + 8 * g;
        #pragma unroll
        for (int r = 0; r < 4; ++r)
          if (tau_base + r > qloc) s[nt][r] = -INFINITY;
      }
    }
    float a0 = fmax3(s[0][0], s[0][1], s[0][2]);
    float a1 = fmax3(s[0][3], s[1][0], s[1][1]);
    float a2 = fmax3(s[1][2], s[1][3], s[2][0]);
    float a3 = fmax3(s[2][1], s[2][2], s[2][3]);
    float a4 = fmax3(s[3][0], s[3][1], s[3][2]);
    float pm = fmax3(fmax3(a0, a1, s[3][3]), fmax3(a2, a3, a4), -INFINITY);
    pm = fmaxf(pm, __shfl_xor(pm, 16));
    pm = fmaxf(pm, __shfl_xor(pm, 32));
    float fac = 1.0f;
    if (!__all(pm - m_ <= 8.0f)) {  // defer-max (T13)
      const float mn = fmaxf(m_, pm);
      fac = fast_exp2(m_ - mn);
      m_ = mn;
      #pragma unroll
      for (int nt = 0; nt < 4; ++nt) acc[nt] *= fac;
    }
    #pragma unroll
    for (int nt = 0; nt < 4; ++nt)
      #pragma unroll
      for (int r = 0; r < 4; ++r) s[nt][r] = fast_exp2(s[nt][r] - m_);
    float b0 = (s[0][0] + s[0][1]) + (s[0][2] + s[0][3]);
    float b1 = (s[1][0] + s[1][1]) + (s[1][2] + s[1][3]);
    float b2 = (s[2][0] + s[2][1]) + (s[2][2] + s[2][3]);
    float b3 = (s[3][0] + s[3][1]) + (s[3][2] + s[3][3]);
    l_ = l_ * fac + ((b0 + b1) + (b2 + b3));  // per-lane partial, no shfl
    u32x4 t0, t1;
    t0[0] = cvt_pk_bf16(s[0][0], s[0][1]); t0[1] = cvt_pk_bf16(s[0][2], s[0][3]);
    t0[2] = cvt_pk_bf16(s[1][0], s[1][1]); t0[3] = cvt_pk_bf16(s[1][2], s[1][3]);
    t1[0] = cvt_pk_bf16(s[2][0], s[2][1]); t1[1] = cvt_pk_bf16(s[2][2], s[2][3]);
    t1[2] = cvt_pk_bf16(s[3][0], s[3][1]); t1[3] = cvt_pk_bf16(s[3][2], s[3][3]);
    pf0 = __builtin_bit_cast(bf16x8, t0);
    pf1 = __builtin_bit_cast(bf16x8, t1);
  };

  auto PV = [&](bf16x8 pf0, bf16x8 pf1) {  // pure register MFMA
    __builtin_amdgcn_s_setprio(1);
    #pragma unroll
    for (int nt = 0; nt < 4; ++nt) {
      acc[nt] = __builtin_amdgcn_mfma_f32_16x16x32_bf16(vreg[2 * nt], pf0, acc[nt], 0, 0, 0);
      acc[nt] = __builtin_amdgcn_mfma_f32_16x16x32_bf16(vreg[2 * nt + 1], pf1, acc[nt], 0, 0, 0);
    }
    __builtin_amdgcn_s_setprio(0);
  };

  auto BODY = [&](int t, f32x4 (&cur)[4], f32x4 (&nxt)[4]) {
    const bool haveN = (t + 1 <= qt);
    if (haveN) STAGE_V(t + 1, (t + 1) & 1);
    if (t + 2 <= qt) STAGE_K(t + 2, (t + 2) % 3);
    if (haveN) QK_LOAD((t + 1) % 3);
    V_LOAD(t & 1);
    bf16x8 pf0, pf1;
    SM(cur, t == qt, pf0, pf1);   // VALU chain overlaps the 16 ds_read latencies
    if (haveN) QK_MMA(nxt);
    PV(pf0, pf1);
    __syncthreads();
  };

  // prologue
  STAGE_K(0, 0);
  STAGE_V(0, 0);
  if (qt >= 1) STAGE_K(1, 1);
  __syncthreads();
  f32x4 sA[4], sB[4];
  QK_LOAD(0);
  QK_MMA(sA);

  int t = 0;
  while (true) {
    BODY(t, sA, sB); if (++t > qt) break;
    BODY(t, sB, sA); if (++t > qt) break;
  }

  // ---- epilogue: combine per-lane l, store O^T[d=nt*16+4g+r][qrow] ----
  float lsum = l_;
  lsum += __shfl_xor(lsum, 16);
  lsum += __shfl_xor(lsum, 32);
  const float inv = 1.0f / lsum;
  float* dst = Oh + (size_t)qrow * 64;
  #pragma unroll
  for (int nt = 0; nt < 4; ++nt) {
    f32x4 v = acc[nt];
    v *= inv;
    *(f32x4*)(dst + nt * 16 + 4 * g) = v;
  }
}

extern "C" void kernel_launch(void* const* d_in, const int* in_sizes, int n_in,
                              void* d_out, int out_size, void* d_ws, size_t ws_size,
                              hipStream_t stream) {
  const float* Q = (const float*)d_in[0];
  const float* K = (const float*)d_in[1];
  const float* V = (const float*)d_in[2];
  float* O = (float*)d_out;
  const size_t NE = (size_t)B_ * H_ * S_ * D_;  // 4194304
  if (ws_size >= 2 * NE * sizeof(ushort_t)) {
    ushort_t* kg = (ushort_t*)d_ws;
    prepack<<<1024, 256, 0, stream>>>(K, V, kg, kg + NE);
    attn8<1><<<dim3(32, 32), 256, 0, stream>>>(Q, K, V, kg, kg + NE, O);
  } else {
    attn8<0><<<dim3(32, 32), 256, 0, stream>>>(Q, K, V, nullptr, nullptr, O);
  }
}

// Round 9
// 55.949 us; speedup vs baseline: 2.1735x; 2.1735x over previous
//
#include <hip/hip_runtime.h>
#include <hip/hip_bf16.h>

#define B_ 2
#define H_ 16
#define S_ 2048
#define D_ 64

typedef __attribute__((ext_vector_type(8))) short bf16x8;
typedef __attribute__((ext_vector_type(8))) unsigned short u16x8;
typedef __attribute__((ext_vector_type(4))) unsigned int u32x4;
typedef __attribute__((ext_vector_type(4))) float f32x4;
typedef unsigned short ushort_t;

#define SCALE 0.18033688011112042f  // (1/sqrt(64)) * log2(e)

__device__ __forceinline__ unsigned short f2bf(float x) {
  unsigned int u = __builtin_bit_cast(unsigned int, x);
  unsigned int r = (u + 0x7FFFu + ((u >> 16) & 1u)) >> 16;
  return (unsigned short)r;
}

__device__ __forceinline__ unsigned int cvt_pk_bf16(float lo, float hi) {
  unsigned int r;
  asm("v_cvt_pk_bf16_f32 %0, %1, %2" : "=v"(r) : "v"(lo), "v"(hi));
  return r;
}

// raw v_exp_f32 (2^x). Safe here: arg <= 8; -inf -> 0.
__device__ __forceinline__ float fast_exp2(float x) {
  float r;
  asm("v_exp_f32 %0, %1" : "=v"(r) : "v"(x));
  return r;
}

__device__ __forceinline__ float fmax3(float a, float b, float c) {
  return fmaxf(fmaxf(a, b), c);
}

// sigma: LDS row rl holds K row sigma(rl); bit permute (b5 b4 b3 b2 b1 b0) ->
// (b5 b3 b2 b4 b1 b0). Makes QK^T D-layout == PV B-frag order (P stays in reg).
__device__ __forceinline__ int sigma_row(int rl) {
  return (rl & 0x23) | ((rl & 0x0C) << 1) | ((rl & 0x10) >> 2);
}

#define GLL16(gp, lp)                                                          \
  __builtin_amdgcn_global_load_lds(                                            \
      (const __attribute__((address_space(1))) unsigned int*)(gp),             \
      (__attribute__((address_space(3))) unsigned int*)(lp), 16, 0, 0)

// ---------------- prepass: K/V fp32 -> bf16, swizzle + K-row-permute baked --
__global__ void prepack(const float* __restrict__ Kf, const float* __restrict__ Vf,
                        ushort_t* __restrict__ Kg, ushort_t* __restrict__ Vtg) {
  const int blk = blockIdx.x;  // bh*32 + t
  const int tid = threadIdx.x;
  const int bh = blk >> 5, t = blk & 31;
  const float* srcK = Kf + ((size_t)bh * S_ + (size_t)t * 64) * D_;
  const float* srcV = Vf + ((size_t)bh * S_ + (size_t)t * 64) * D_;
  ushort_t* dK = Kg + (size_t)blk * 4096;
  ushort_t* dV = Vtg + (size_t)blk * 4096;
  for (int is = 0; is < 2; ++is) {
    const int e = is * 2048 + tid * 8;
    {  // K with sigma row permute
      const int rl = e >> 6, pos = (e >> 3) & 7, ch = pos ^ (rl & 7);
      const float* sp = srcK + sigma_row(rl) * 64 + ch * 8;
      float4 a = *(const float4*)sp;
      float4 b = *(const float4*)(sp + 4);
      u16x8 w;
      w[0] = f2bf(a.x); w[1] = f2bf(a.y); w[2] = f2bf(a.z); w[3] = f2bf(a.w);
      w[4] = f2bf(b.x); w[5] = f2bf(b.y); w[6] = f2bf(b.z); w[7] = f2bf(b.w);
      *(u16x8*)(dK + e) = w;
    }
    {  // V transposed
      const int d0 = e >> 6, pos = (e >> 3) & 7, ch = pos ^ (d0 & 7);
      u16x8 w;
      for (int i = 0; i < 8; ++i) w[i] = f2bf(srcV[(size_t)(ch * 8 + i) * 64 + d0]);
      *(u16x8*)(dV + e) = w;
    }
  }
}

// ---------------- split kernel: <=16 kv tiles per block, balanced grid ------
// y decodes an LPT-ordered item table: (qt,c). qt<=15: single chunk, final O.
// qt>=16: chunks c0 (tiles 0..15), c1 (tiles 16..qt) write partials (O',m,l).
__launch_bounds__(256, 5)
__global__ void attn_split(const float* __restrict__ Qf, const ushort_t* __restrict__ Kg,
                           const ushort_t* __restrict__ Vtg, float* __restrict__ O,
                           float* __restrict__ PO, float* __restrict__ ML) {
  const int bh = blockIdx.x;  // 0..31
  const int y = blockIdx.y;   // 0..47, LPT order
  int qt, c;
  if (y == 0) { qt = 15; c = 0; }
  else if (y <= 16) { qt = 15 + y; c = 0; }
  else if (y == 17) { qt = 31; c = 1; }
  else { const int p = y - 18, k = 15 - (p >> 1);
         if (p & 1) { qt = k + 15; c = 1; } else { qt = k - 1; c = 0; } }
  const int t0 = c << 4;
  const int t1 = (qt < t0 + 15) ? qt : (t0 + 15);

  const int tid = threadIdx.x;
  const int wave = tid >> 6, lane = tid & 63;
  const int col = lane & 15, g = lane >> 4;

  __shared__ __align__(16) ushort_t Kl[2][64][64];
  __shared__ __align__(16) ushort_t Vt[2][64][64];

  // Q fragment: lane holds Q[qrow][32kk+8g+i]
  const int qrow = qt * 64 + wave * 16 + col;
  bf16x8 qf[2];
  {
    const float* Qh = Qf + (size_t)bh * S_ * D_;
    for (int kk = 0; kk < 2; ++kk) {
      const float* p = Qh + (size_t)qrow * 64 + kk * 32 + g * 8;
      float4 a = *(const float4*)p;
      float4 b = *(const float4*)(p + 4);
      float v[8] = {a.x, a.y, a.z, a.w, b.x, b.y, b.z, b.w};
      bf16x8 w;
      for (int i = 0; i < 8; ++i) w[i] = (short)f2bf(v[i] * SCALE);
      qf[kk] = w;
    }
  }

  f32x4 acc[4] = {};
  float m_ = -INFINITY, l_ = 0.0f;  // l_ per-lane partial

  const int ch0 = (g ^ (col & 7)) << 3;
  const int ch1 = ((4 | g) ^ (col & 7)) << 3;

  auto STAGE = [&](int t, int b) {
    const ushort_t* kg = Kg + ((size_t)(bh * 32 + t)) * 4096;
    const ushort_t* vg = Vtg + ((size_t)(bh * 32 + t)) * 4096;
    GLL16(kg + tid * 8,        &Kl[b][0][0] + tid * 8);
    GLL16(kg + 2048 + tid * 8, &Kl[b][0][0] + 2048 + tid * 8);
    GLL16(vg + tid * 8,        &Vt[b][0][0] + tid * 8);
    GLL16(vg + 2048 + tid * 8, &Vt[b][0][0] + 2048 + tid * 8);
  };

  auto COMPUTE = [&](int b, bool diag) {
    f32x4 s[4] = {{0,0,0,0},{0,0,0,0},{0,0,0,0},{0,0,0,0}};
    __builtin_amdgcn_s_setprio(1);
    #pragma unroll
    for (int nt = 0; nt < 4; ++nt) {
      const ushort_t* row = &Kl[b][nt * 16 + col][0];
      const bf16x8 kf0 = *(const bf16x8*)(row + ch0);
      const bf16x8 kf1 = *(const bf16x8*)(row + ch1);
      s[nt] = __builtin_amdgcn_mfma_f32_16x16x32_bf16(kf0, qf[0], s[nt], 0, 0, 0);
      s[nt] = __builtin_amdgcn_mfma_f32_16x16x32_bf16(kf1, qf[1], s[nt], 0, 0, 0);
    }
    __builtin_amdgcn_s_setprio(0);
    if (diag) {
      const int qloc = wave * 16 + col;
      #pragma unroll
      for (int nt = 0; nt < 4; ++nt) {
        const int tau_base = 32 * (nt >> 1) + 4 * (nt & 1) + 8 * g;
        #pragma unroll
        for (int r = 0; r < 4; ++r)
          if (tau_base + r > qloc) s[nt][r] = -INFINITY;
      }
    }
    float a0 = fmax3(s[0][0], s[0][1], s[0][2]);
    float a1 = fmax3(s[0][3], s[1][0], s[1][1]);
    float a2 = fmax3(s[1][2], s[1][3], s[2][0]);
    float a3 = fmax3(s[2][1], s[2][2], s[2][3]);
    float a4 = fmax3(s[3][0], s[3][1], s[3][2]);
    float pm = fmax3(fmax3(a0, a1, s[3][3]), fmax3(a2, a3, a4), -INFINITY);
    pm = fmaxf(pm, __shfl_xor(pm, 16));
    pm = fmaxf(pm, __shfl_xor(pm, 32));
    float fac = 1.0f;
    if (!__all(pm - m_ <= 8.0f)) {  // defer-max (T13)
      const float mn = fmaxf(m_, pm);
      fac = fast_exp2(m_ - mn);
      m_ = mn;
      #pragma unroll
      for (int nt = 0; nt < 4; ++nt) acc[nt] *= fac;
    }
    #pragma unroll
    for (int nt = 0; nt < 4; ++nt)
      #pragma unroll
      for (int r = 0; r < 4; ++r) s[nt][r] = fast_exp2(s[nt][r] - m_);
    float b0 = (s[0][0] + s[0][1]) + (s[0][2] + s[0][3]);
    float b1 = (s[1][0] + s[1][1]) + (s[1][2] + s[1][3]);
    float b2 = (s[2][0] + s[2][1]) + (s[2][2] + s[2][3]);
    float b3 = (s[3][0] + s[3][1]) + (s[3][2] + s[3][3]);
    l_ = l_ * fac + ((b0 + b1) + (b2 + b3));
    u32x4 w0, w1;
    w0[0] = cvt_pk_bf16(s[0][0], s[0][1]); w0[1] = cvt_pk_bf16(s[0][2], s[0][3]);
    w0[2] = cvt_pk_bf16(s[1][0], s[1][1]); w0[3] = cvt_pk_bf16(s[1][2], s[1][3]);
    w1[0] = cvt_pk_bf16(s[2][0], s[2][1]); w1[1] = cvt_pk_bf16(s[2][2], s[2][3]);
    w1[2] = cvt_pk_bf16(s[3][0], s[3][1]); w1[3] = cvt_pk_bf16(s[3][2], s[3][3]);
    const bf16x8 pf0 = __builtin_bit_cast(bf16x8, w0);
    const bf16x8 pf1 = __builtin_bit_cast(bf16x8, w1);
    __builtin_amdgcn_s_setprio(1);
    #pragma unroll
    for (int nt = 0; nt < 4; ++nt) {
      const ushort_t* row = &Vt[b][nt * 16 + col][0];
      const bf16x8 vf0 = *(const bf16x8*)(row + ch0);
      const bf16x8 vf1 = *(const bf16x8*)(row + ch1);
      acc[nt] = __builtin_amdgcn_mfma_f32_16x16x32_bf16(vf0, pf0, acc[nt], 0, 0, 0);
      acc[nt] = __builtin_amdgcn_mfma_f32_16x16x32_bf16(vf1, pf1, acc[nt], 0, 0, 0);
    }
    __builtin_amdgcn_s_setprio(0);
  };

  int cur = 0;
  STAGE(t0, 0);
  __syncthreads();
  for (int t = t0; t <= t1; ++t) {
    if (t < t1) STAGE(t + 1, cur ^ 1);
    COMPUTE(cur, t == qt);
    __syncthreads();
    cur ^= 1;
  }

  float lsum = l_;
  lsum += __shfl_xor(lsum, 16);
  lsum += __shfl_xor(lsum, 32);
  const int rowloc = wave * 16 + col;  // 0..63
  if (qt <= 15) {
    const float inv = 1.0f / lsum;
    float* dst = O + (size_t)bh * S_ * D_ + (size_t)qrow * 64;
    #pragma unroll
    for (int nt = 0; nt < 4; ++nt) {
      f32x4 v = acc[nt];
      v *= inv;
      *(f32x4*)(dst + nt * 16 + 4 * g) = v;
    }
  } else {
    float* po = PO + (size_t)((((bh << 4) + (qt - 16)) << 1) + c) * 4096;
    #pragma unroll
    for (int nt = 0; nt < 4; ++nt)
      *(f32x4*)(po + rowloc * 64 + nt * 16 + 4 * g) = acc[nt];
    if (g == 0) {
      float* ml = ML + (size_t)((((bh << 4) + (qt - 16)) << 1) + c) * 128 + rowloc * 2;
      ml[0] = m_;
      ml[1] = lsum;
    }
  }
}

// ---------------- merge: combine the two partials for qt >= 16 --------------
__global__ void merge_partials(const float* __restrict__ PO, const float* __restrict__ ML,
                               float* __restrict__ O) {
  const int bh = blockIdx.x;   // 32
  const int q16 = blockIdx.y;  // 16 -> qt = 16+q16
  const int tid = threadIdx.x;
  const int r = tid >> 2, d0 = (tid & 3) << 4;
  const size_t base = (size_t)((bh << 4) + q16) << 1;
  const float* ml0 = ML + base * 128 + r * 2;
  const float* ml1 = ML + (base + 1) * 128 + r * 2;
  const float m0 = ml0[0], l0 = ml0[1], m1 = ml1[0], l1 = ml1[1];
  const float M = fmaxf(m0, m1);
  const float w0 = fast_exp2(m0 - M), w1 = fast_exp2(m1 - M);
  const float inv = 1.0f / (w0 * l0 + w1 * l1);
  const float a = w0 * inv, b = w1 * inv;
  const float* p0 = PO + base * 4096 + r * 64 + d0;
  const float* p1 = PO + (base + 1) * 4096 + r * 64 + d0;
  float* out = O + ((size_t)bh * S_ + (size_t)(16 + q16) * 64 + r) * 64 + d0;
  #pragma unroll
  for (int j = 0; j < 4; ++j) {
    float4 x = *(const float4*)(p0 + 4 * j);
    float4 y = *(const float4*)(p1 + 4 * j);
    float4 o;
    o.x = a * x.x + b * y.x; o.y = a * x.y + b * y.y;
    o.z = a * x.z + b * y.z; o.w = a * x.w + b * y.w;
    *(float4*)(out + 4 * j) = o;
  }
}

// ---------------- fallback: R6 kernel (used only if ws is too small) --------
template <int PRE>
__launch_bounds__(256, 4)
__global__ void attn6(const float* __restrict__ Qf, const float* __restrict__ Kf,
                      const float* __restrict__ Vf, const ushort_t* __restrict__ Kg,
                      const ushort_t* __restrict__ Vtg, float* __restrict__ O) {
  const int bh = blockIdx.x;
  const int qt = 31 - blockIdx.y;
  const int tid = threadIdx.x;
  const int wave = tid >> 6, lane = tid & 63;
  const int col = lane & 15, g = lane >> 4;
  __shared__ __align__(16) ushort_t Kl[2][64][64];
  __shared__ __align__(16) ushort_t Vt[2][64][64];
  float* Oh = O + (size_t)bh * S_ * D_;
  const int qrow = qt * 64 + wave * 16 + col;
  bf16x8 qf[2];
  {
    const float* Qh = Qf + (size_t)bh * S_ * D_;
    for (int kk = 0; kk < 2; ++kk) {
      const float* p = Qh + (size_t)qrow * 64 + kk * 32 + g * 8;
      float4 a = *(const float4*)p;
      float4 b = *(const float4*)(p + 4);
      float v[8] = {a.x, a.y, a.z, a.w, b.x, b.y, b.z, b.w};
      bf16x8 w;
      for (int i = 0; i < 8; ++i) w[i] = (short)f2bf(v[i] * SCALE);
      qf[kk] = w;
    }
  }
  f32x4 acc[4] = {};
  float m_ = -INFINITY, l_ = 0.0f;
  const int ch0 = (g ^ (col & 7)) << 3;
  const int ch1 = ((4 | g) ^ (col & 7)) << 3;
  auto STAGE = [&](int t, int b) {
    if (PRE) {
      const ushort_t* kg = Kg + ((size_t)(bh * 32 + t)) * 4096;
      const ushort_t* vg = Vtg + ((size_t)(bh * 32 + t)) * 4096;
      GLL16(kg + tid * 8,        &Kl[b][0][0] + tid * 8);
      GLL16(kg + 2048 + tid * 8, &Kl[b][0][0] + 2048 + tid * 8);
      GLL16(vg + tid * 8,        &Vt[b][0][0] + tid * 8);
      GLL16(vg + 2048 + tid * 8, &Vt[b][0][0] + 2048 + tid * 8);
    } else {
      const float* Kh = Kf + (size_t)bh * S_ * D_;
      const float* Vh = Vf + (size_t)bh * S_ * D_;
      {
        const int rl = tid >> 2;
        const int c0 = (tid & 3) << 4;
        const float* src = Kh + ((size_t)(t * 64 + sigma_row(rl))) * 64 + c0;
        for (int jj = 0; jj < 2; ++jj) {
          float4 x = *(const float4*)(src + jj * 8);
          float4 y = *(const float4*)(src + jj * 8 + 4);
          u16x8 w;
          w[0] = f2bf(x.x); w[1] = f2bf(x.y); w[2] = f2bf(x.z); w[3] = f2bf(x.w);
          w[4] = f2bf(y.x); w[5] = f2bf(y.y); w[6] = f2bf(y.z); w[7] = f2bf(y.w);
          const int ch = (c0 >> 3) + jj;
          *(u16x8*)&Kl[b][rl][(ch ^ (rl & 7)) << 3] = w;
        }
      }
      {
        const int c = tid & 63;
        const int r0 = (tid >> 6) << 4;
        const float* src = Vh + ((size_t)(t * 64 + r0)) * 64 + c;
        for (int jj = 0; jj < 2; ++jj) {
          u16x8 w;
          for (int i = 0; i < 8; ++i) w[i] = f2bf(src[(size_t)(jj * 8 + i) * 64]);
          const int ch = (r0 >> 3) + jj;
          *(u16x8*)&Vt[b][c][(ch ^ (c & 7)) << 3] = w;
        }
      }
    }
  };
  auto COMPUTE = [&](int b, bool diag) {
    f32x4 s[4] = {{0,0,0,0},{0,0,0,0},{0,0,0,0},{0,0,0,0}};
    __builtin_amdgcn_s_setprio(1);
    for (int nt = 0; nt < 4; ++nt) {
      const ushort_t* row = &Kl[b][nt * 16 + col][0];
      const bf16x8 kf0 = *(const bf16x8*)(row + ch0);
      const bf16x8 kf1 = *(const bf16x8*)(row + ch1);
      s[nt] = __builtin_amdgcn_mfma_f32_16x16x32_bf16(kf0, qf[0], s[nt], 0, 0, 0);
      s[nt] = __builtin_amdgcn_mfma_f32_16x16x32_bf16(kf1, qf[1], s[nt], 0, 0, 0);
    }
    __builtin_amdgcn_s_setprio(0);
    if (diag) {
      const int qloc = wave * 16 + col;
      for (int nt = 0; nt < 4; ++nt) {
        const int tau_base = 32 * (nt >> 1) + 4 * (nt & 1) + 8 * g;
        for (int r = 0; r < 4; ++r)
          if (tau_base + r > qloc) s[nt][r] = -INFINITY;
      }
    }
    float pm = fmaxf(fmaxf(fmaxf(s[0][0], s[0][1]), fmaxf(s[0][2], s[0][3])),
                     fmaxf(fmaxf(s[1][0], s[1][1]), fmaxf(s[1][2], s[1][3])));
    pm = fmaxf(pm, fmaxf(fmaxf(fmaxf(s[2][0], s[2][1]), fmaxf(s[2][2], s[2][3])),
                         fmaxf(fmaxf(s[3][0], s[3][1]), fmaxf(s[3][2], s[3][3]))));
    pm = fmaxf(pm, __shfl_xor(pm, 16));
    pm = fmaxf(pm, __shfl_xor(pm, 32));
    float fac = 1.0f;
    if (!__all(pm - m_ <= 8.0f)) {
      const float mn = fmaxf(m_, pm);
      fac = fast_exp2(m_ - mn);
      m_ = mn;
      for (int nt = 0; nt < 4; ++nt) acc[nt] *= fac;
    }
    float sum = 0.0f;
    for (int nt = 0; nt < 4; ++nt)
      for (int r = 0; r < 4; ++r) {
        const float p = fast_exp2(s[nt][r] - m_);
        s[nt][r] = p;
        sum += p;
      }
    l_ = l_ * fac + sum;
    u32x4 t0, t1;
    t0[0] = cvt_pk_bf16(s[0][0], s[0][1]); t0[1] = cvt_pk_bf16(s[0][2], s[0][3]);
    t0[2] = cvt_pk_bf16(s[1][0], s[1][1]); t0[3] = cvt_pk_bf16(s[1][2], s[1][3]);
    t1[0] = cvt_pk_bf16(s[2][0], s[2][1]); t1[1] = cvt_pk_bf16(s[2][2], s[2][3]);
    t1[2] = cvt_pk_bf16(s[3][0], s[3][1]); t1[3] = cvt_pk_bf16(s[3][2], s[3][3]);
    const bf16x8 pf0 = __builtin_bit_cast(bf16x8, t0);
    const bf16x8 pf1 = __builtin_bit_cast(bf16x8, t1);
    __builtin_amdgcn_s_setprio(1);
    for (int nt = 0; nt < 4; ++nt) {
      const ushort_t* row = &Vt[b][nt * 16 + col][0];
      const bf16x8 vf0 = *(const bf16x8*)(row + ch0);
      const bf16x8 vf1 = *(const bf16x8*)(row + ch1);
      acc[nt] = __builtin_amdgcn_mfma_f32_16x16x32_bf16(vf0, pf0, acc[nt], 0, 0, 0);
      acc[nt] = __builtin_amdgcn_mfma_f32_16x16x32_bf16(vf1, pf1, acc[nt], 0, 0, 0);
    }
    __builtin_amdgcn_s_setprio(0);
  };
  int cur = 0;
  STAGE(0, 0);
  __syncthreads();
  for (int t = 0; t <= qt; ++t) {
    if (t < qt) STAGE(t + 1, cur ^ 1);
    COMPUTE(cur, t == qt);
    __syncthreads();
    cur ^= 1;
  }
  float lsum = l_;
  lsum += __shfl_xor(lsum, 16);
  lsum += __shfl_xor(lsum, 32);
  const float inv = 1.0f / lsum;
  float* dst = Oh + (size_t)qrow * 64;
  for (int nt = 0; nt < 4; ++nt) {
    f32x4 v = acc[nt];
    v *= inv;
    *(f32x4*)(dst + nt * 16 + 4 * g) = v;
  }
}

extern "C" void kernel_launch(void* const* d_in, const int* in_sizes, int n_in,
                              void* d_out, int out_size, void* d_ws, size_t ws_size,
                              hipStream_t stream) {
  const float* Q = (const float*)d_in[0];
  const float* K = (const float*)d_in[1];
  const float* V = (const float*)d_in[2];
  float* O = (float*)d_out;
  const size_t NE = (size_t)B_ * H_ * S_ * D_;            // 4194304
  const size_t needK = 2 * NE * sizeof(ushort_t);         // 16777216
  const size_t PO_elems = 32ull * 16 * 2 * 4096;          // 4194304 floats
  const size_t ML_elems = 32ull * 16 * 2 * 128;           // 131072 floats
  const size_t needSplit = needK + (PO_elems + ML_elems) * sizeof(float);  // 34078720
  if (ws_size >= needSplit) {
    ushort_t* kg = (ushort_t*)d_ws;
    float* PO = (float*)((char*)d_ws + needK);
    float* ML = PO + PO_elems;
    prepack<<<1024, 256, 0, stream>>>(K, V, kg, kg + NE);
    attn_split<<<dim3(32, 48), 256, 0, stream>>>(Q, kg, kg + NE, O, PO, ML);
    merge_partials<<<dim3(32, 16), 256, 0, stream>>>(PO, ML, O);
  } else if (ws_size >= needK) {
    ushort_t* kg = (ushort_t*)d_ws;
    prepack<<<1024, 256, 0, stream>>>(K, V, kg, kg + NE);
    attn6<1><<<dim3(32, 32), 256, 0, stream>>>(Q, K, V, kg, kg + NE, O);
  } else {
    attn6<0><<<dim3(32, 32), 256, 0, stream>>>(Q, K, V, nullptr, nullptr, O);
  }
}

// Round 10
// 54.834 us; speedup vs baseline: 2.2176x; 1.0203x over previous
//
#include <hip/hip_runtime.h>
#include <hip/hip_bf16.h>

#define B_ 2
#define H_ 16
#define S_ 2048
#define D_ 64

typedef __attribute__((ext_vector_type(8))) short bf16x8;
typedef __attribute__((ext_vector_type(8))) unsigned short u16x8;
typedef __attribute__((ext_vector_type(4))) unsigned int u32x4;
typedef __attribute__((ext_vector_type(4))) float f32x4;
typedef unsigned short ushort_t;

#define SCALE 0.18033688011112042f  // (1/sqrt(64)) * log2(e)

__device__ __forceinline__ unsigned short f2bf(float x) {
  unsigned int u = __builtin_bit_cast(unsigned int, x);
  unsigned int r = (u + 0x7FFFu + ((u >> 16) & 1u)) >> 16;
  return (unsigned short)r;
}

__device__ __forceinline__ unsigned int cvt_pk_bf16(float lo, float hi) {
  unsigned int r;
  asm("v_cvt_pk_bf16_f32 %0, %1, %2" : "=v"(r) : "v"(lo), "v"(hi));
  return r;
}

// raw v_exp_f32 (2^x). Safe here: arg <= 8; -inf -> 0.
__device__ __forceinline__ float fast_exp2(float x) {
  float r;
  asm("v_exp_f32 %0, %1" : "=v"(r) : "v"(x));
  return r;
}

__device__ __forceinline__ float fmax3(float a, float b, float c) {
  return fmaxf(fmaxf(a, b), c);
}

// sigma32: LDS row lr (5 bits [nt0 g1 g0 r1 r0]) holds K row kv = 8g+4nt0+r
// ([g1 g0 nt0 r1 r0]). Makes QK^T D-layout == PV B-frag order (P in regs).
__device__ __forceinline__ int sigma32(int lr) {
  return (lr & 3) | ((lr & 0x0C) << 1) | ((lr & 0x10) >> 2);
}

#define GLL16(gp, lp)                                                          \
  __builtin_amdgcn_global_load_lds(                                            \
      (const __attribute__((address_space(1))) unsigned int*)(gp),             \
      (__attribute__((address_space(3))) unsigned int*)(lp), 16, 0, 0)

// ---------------- prepass: K/V fp32 -> bf16, 32-row tiles, layouts baked ----
// K tile (per bh,kt; 2048 ushorts): e: lr=e>>6, pos=(e>>3)&7, ch=pos^(lr&7);
//   content = K[32kt + sigma32(lr)][ch*8 + i]
// Vt tile (2048 ushorts): e: d=e>>5, pos2=(e>>3)&3, ch2=pos2^(d&3);
//   content = V[32kt + ch2*8 + i][d]
__global__ void prepack32(const float* __restrict__ Kf, const float* __restrict__ Vf,
                          ushort_t* __restrict__ Kg, ushort_t* __restrict__ Vtg) {
  const int blk = blockIdx.x;  // bh*64 + kt
  const int tid = threadIdx.x;
  const int bh = blk >> 6, kt = blk & 63;
  const float* srcK = Kf + ((size_t)bh * S_ + (size_t)kt * 32) * D_;
  const float* srcV = Vf + ((size_t)bh * S_ + (size_t)kt * 32) * D_;
  ushort_t* dK = Kg + (size_t)blk * 2048;
  ushort_t* dV = Vtg + (size_t)blk * 2048;
  const int e = tid * 8;
  {  // K with sigma32 row permute
    const int lr = e >> 6, pos = (e >> 3) & 7, ch = pos ^ (lr & 7);
    const float* sp = srcK + sigma32(lr) * 64 + ch * 8;
    float4 a = *(const float4*)sp;
    float4 b = *(const float4*)(sp + 4);
    u16x8 w;
    w[0] = f2bf(a.x); w[1] = f2bf(a.y); w[2] = f2bf(a.z); w[3] = f2bf(a.w);
    w[4] = f2bf(b.x); w[5] = f2bf(b.y); w[6] = f2bf(b.z); w[7] = f2bf(b.w);
    *(u16x8*)(dK + e) = w;
  }
  {  // V transposed
    const int d0 = e >> 5, pos2 = (e >> 3) & 3, ch2 = pos2 ^ (d0 & 3);
    u16x8 w;
    for (int i = 0; i < 8; ++i) w[i] = f2bf(srcV[(size_t)(ch2 * 8 + i) * 64 + d0]);
    *(u16x8*)(dV + e) = w;
  }
}

// ---------------- split kernel: 32-kv tiles, <=32 tiles/block, 8 blocks/CU --
// y decodes LPT-ordered items (qt,c). qt<=15: single chunk (kt 0..2qt+1), O.
// qt>=16: c0 (kt 0..31), c1 (kt 32..2qt+1) write partials (O',m,l).
__launch_bounds__(256, 8)
__global__ void attn_s32(const float* __restrict__ Qf, const ushort_t* __restrict__ Kg,
                         const ushort_t* __restrict__ Vtg, float* __restrict__ O,
                         float* __restrict__ PO, float* __restrict__ ML) {
  const int bh = blockIdx.x;  // 0..31
  const int y = blockIdx.y;   // 0..47, LPT order
  int qt, c;
  if (y == 0) { qt = 15; c = 0; }
  else if (y <= 16) { qt = 15 + y; c = 0; }
  else if (y == 17) { qt = 31; c = 1; }
  else { const int p = y - 18, k = 15 - (p >> 1);
         if (p & 1) { qt = k + 15; c = 1; } else { qt = k - 1; c = 0; } }
  const int t0k = c << 5;                       // first kv tile
  const int tEnd = 2 * qt + 1;
  const int t1k = (tEnd < t0k + 31) ? tEnd : (t0k + 31);

  const int tid = threadIdx.x;
  const int wave = tid >> 6, lane = tid & 63;
  const int col = lane & 15, g = lane >> 4;

  __shared__ __align__(16) ushort_t Kl[2][32][64];  // 8 KB
  __shared__ __align__(16) ushort_t Vt[2][64][32];  // 8 KB

  // Q fragment: lane holds Q[qrow][32kk+8g+i]
  const int qrow = qt * 64 + wave * 16 + col;
  bf16x8 qf[2];
  {
    const float* Qh = Qf + (size_t)bh * S_ * D_;
    for (int kk = 0; kk < 2; ++kk) {
      const float* p = Qh + (size_t)qrow * 64 + kk * 32 + g * 8;
      float4 a = *(const float4*)p;
      float4 b = *(const float4*)(p + 4);
      float v[8] = {a.x, a.y, a.z, a.w, b.x, b.y, b.z, b.w};
      bf16x8 w;
      for (int i = 0; i < 8; ++i) w[i] = (short)f2bf(v[i] * SCALE);
      qf[kk] = w;
    }
  }

  f32x4 acc[4] = {};
  float m_ = -INFINITY, l_ = 0.0f;  // l_ per-lane partial

  const int ch0 = (g ^ (col & 7)) << 3;        // K chunk, kk=0 (ushort off)
  const int ch1 = ((4 | g) ^ (col & 7)) << 3;  // K chunk, kk=1
  const int chV = (g ^ (col & 3)) << 3;        // V chunk (4-chunk rows)

  auto STAGE = [&](int kt, int b) {
    const ushort_t* kg = Kg + ((size_t)(bh * 64 + kt)) * 2048;
    const ushort_t* vg = Vtg + ((size_t)(bh * 64 + kt)) * 2048;
    GLL16(kg + tid * 8, &Kl[b][0][0] + tid * 8);
    GLL16(vg + tid * 8, &Vt[b][0][0] + tid * 8);
  };

  auto COMPUTE = [&](int kt, int b, bool diag) {
    f32x4 s[2] = {{0,0,0,0},{0,0,0,0}};
    __builtin_amdgcn_s_setprio(1);
    #pragma unroll
    for (int nt = 0; nt < 2; ++nt) {
      const ushort_t* row = &Kl[b][nt * 16 + col][0];
      const bf16x8 kf0 = *(const bf16x8*)(row + ch0);
      const bf16x8 kf1 = *(const bf16x8*)(row + ch1);
      s[nt] = __builtin_amdgcn_mfma_f32_16x16x32_bf16(kf0, qf[0], s[nt], 0, 0, 0);
      s[nt] = __builtin_amdgcn_mfma_f32_16x16x32_bf16(kf1, qf[1], s[nt], 0, 0, 0);
    }
    __builtin_amdgcn_s_setprio(0);
    if (diag) {  // kv = 32kt + 8g + 4nt + r  vs  q = qt*64 + wave*16 + col
      const int qg = qt * 64 + wave * 16 + col - 32 * kt - 8 * g;
      #pragma unroll
      for (int nt = 0; nt < 2; ++nt)
        #pragma unroll
        for (int r = 0; r < 4; ++r)
          if (4 * nt + r > qg) s[nt][r] = -INFINITY;
    }
    float pm = fmax3(fmax3(s[0][0], s[0][1], s[0][2]),
                     fmax3(s[0][3], s[1][0], s[1][1]),
                     fmaxf(fmaxf(s[1][2], s[1][3]), -INFINITY));
    pm = fmaxf(pm, __shfl_xor(pm, 16));
    pm = fmaxf(pm, __shfl_xor(pm, 32));
    float fac = 1.0f;
    if (!__all(pm - m_ <= 8.0f)) {  // defer-max (T13)
      const float mn = fmaxf(m_, pm);
      fac = fast_exp2(m_ - mn);
      m_ = mn;
      #pragma unroll
      for (int nt = 0; nt < 4; ++nt) acc[nt] *= fac;
    }
    #pragma unroll
    for (int nt = 0; nt < 2; ++nt)
      #pragma unroll
      for (int r = 0; r < 4; ++r) s[nt][r] = fast_exp2(s[nt][r] - m_);
    const float b0 = (s[0][0] + s[0][1]) + (s[0][2] + s[0][3]);
    const float b1 = (s[1][0] + s[1][1]) + (s[1][2] + s[1][3]);
    l_ = l_ * fac + (b0 + b1);
    u32x4 w;  // pf = [s0.0..3, s1.0..3] = P^T[kv 8g+0..7][q] (sigma32-aligned)
    w[0] = cvt_pk_bf16(s[0][0], s[0][1]); w[1] = cvt_pk_bf16(s[0][2], s[0][3]);
    w[2] = cvt_pk_bf16(s[1][0], s[1][1]); w[3] = cvt_pk_bf16(s[1][2], s[1][3]);
    const bf16x8 pf = __builtin_bit_cast(bf16x8, w);
    __builtin_amdgcn_s_setprio(1);
    #pragma unroll
    for (int nt = 0; nt < 4; ++nt) {
      const bf16x8 vf = *(const bf16x8*)(&Vt[b][nt * 16 + col][0] + chV);
      acc[nt] = __builtin_amdgcn_mfma_f32_16x16x32_bf16(vf, pf, acc[nt], 0, 0, 0);
    }
    __builtin_amdgcn_s_setprio(0);
  };

  int cur = 0;
  STAGE(t0k, 0);
  __syncthreads();
  const int diag0 = 2 * qt;  // tiles >= this need masking
  for (int kt = t0k; kt <= t1k; ++kt) {
    if (kt < t1k) STAGE(kt + 1, cur ^ 1);
    COMPUTE(kt, cur, kt >= diag0);
    __syncthreads();
    cur ^= 1;
  }

  float lsum = l_;
  lsum += __shfl_xor(lsum, 16);
  lsum += __shfl_xor(lsum, 32);
  const int rowloc = wave * 16 + col;  // 0..63
  if (qt <= 15) {
    const float inv = 1.0f / lsum;
    float* dst = O + (size_t)bh * S_ * D_ + (size_t)qrow * 64;
    #pragma unroll
    for (int nt = 0; nt < 4; ++nt) {
      f32x4 v = acc[nt];
      v *= inv;
      *(f32x4*)(dst + nt * 16 + 4 * g) = v;
    }
  } else {
    float* po = PO + (size_t)((((bh << 4) + (qt - 16)) << 1) + c) * 4096;
    #pragma unroll
    for (int nt = 0; nt < 4; ++nt)
      *(f32x4*)(po + rowloc * 64 + nt * 16 + 4 * g) = acc[nt];
    if (g == 0) {
      float* ml = ML + (size_t)((((bh << 4) + (qt - 16)) << 1) + c) * 128 + rowloc * 2;
      ml[0] = m_;
      ml[1] = lsum;
    }
  }
}

// ---------------- merge: combine the two partials for qt >= 16 --------------
__global__ void merge_partials(const float* __restrict__ PO, const float* __restrict__ ML,
                               float* __restrict__ O) {
  const int bh = blockIdx.x;   // 32
  const int q16 = blockIdx.y;  // 16 -> qt = 16+q16
  const int tid = threadIdx.x;
  const int r = tid >> 2, d0 = (tid & 3) << 4;
  const size_t base = (size_t)((bh << 4) + q16) << 1;
  const float* ml0 = ML + base * 128 + r * 2;
  const float* ml1 = ML + (base + 1) * 128 + r * 2;
  const float m0 = ml0[0], l0 = ml0[1], m1 = ml1[0], l1 = ml1[1];
  const float M = fmaxf(m0, m1);
  const float w0 = fast_exp2(m0 - M), w1 = fast_exp2(m1 - M);
  const float inv = 1.0f / (w0 * l0 + w1 * l1);
  const float a = w0 * inv, b = w1 * inv;
  const float* p0 = PO + base * 4096 + r * 64 + d0;
  const float* p1 = PO + (base + 1) * 4096 + r * 64 + d0;
  float* out = O + ((size_t)bh * S_ + (size_t)(16 + q16) * 64 + r) * 64 + d0;
  #pragma unroll
  for (int j = 0; j < 4; ++j) {
    float4 x = *(const float4*)(p0 + 4 * j);
    float4 y = *(const float4*)(p1 + 4 * j);
    float4 o;
    o.x = a * x.x + b * y.x; o.y = a * x.y + b * y.y;
    o.z = a * x.z + b * y.z; o.w = a * x.w + b * y.w;
    *(float4*)(out + 4 * j) = o;
  }
}

// ---------------- fallback: direct-from-fp32 flash attn (ws too small) ------
__device__ __forceinline__ int sigma_row64(int rl) {
  return (rl & 0x23) | ((rl & 0x0C) << 1) | ((rl & 0x10) >> 2);
}
__launch_bounds__(256, 4)
__global__ void attn_fb(const float* __restrict__ Qf, const float* __restrict__ Kf,
                        const float* __restrict__ Vf, float* __restrict__ O) {
  const int bh = blockIdx.x;
  const int qt = 31 - blockIdx.y;
  const int tid = threadIdx.x;
  const int wave = tid >> 6, lane = tid & 63;
  const int col = lane & 15, g = lane >> 4;
  __shared__ __align__(16) ushort_t Kl[2][64][64];
  __shared__ __align__(16) ushort_t Vt[2][64][64];
  const int qrow = qt * 64 + wave * 16 + col;
  bf16x8 qf[2];
  {
    const float* Qh = Qf + (size_t)bh * S_ * D_;
    for (int kk = 0; kk < 2; ++kk) {
      const float* p = Qh + (size_t)qrow * 64 + kk * 32 + g * 8;
      float4 a = *(const float4*)p;
      float4 b = *(const float4*)(p + 4);
      float v[8] = {a.x, a.y, a.z, a.w, b.x, b.y, b.z, b.w};
      bf16x8 w;
      for (int i = 0; i < 8; ++i) w[i] = (short)f2bf(v[i] * SCALE);
      qf[kk] = w;
    }
  }
  f32x4 acc[4] = {};
  float m_ = -INFINITY, l_ = 0.0f;
  const int ch0 = (g ^ (col & 7)) << 3;
  const int ch1 = ((4 | g) ^ (col & 7)) << 3;
  auto STAGE = [&](int t, int b) {
    const float* Kh = Kf + (size_t)bh * S_ * D_;
    const float* Vh = Vf + (size_t)bh * S_ * D_;
    {
      const int rl = tid >> 2;
      const int c0 = (tid & 3) << 4;
      const float* src = Kh + ((size_t)(t * 64 + sigma_row64(rl))) * 64 + c0;
      for (int jj = 0; jj < 2; ++jj) {
        float4 x = *(const float4*)(src + jj * 8);
        float4 y = *(const float4*)(src + jj * 8 + 4);
        u16x8 w;
        w[0] = f2bf(x.x); w[1] = f2bf(x.y); w[2] = f2bf(x.z); w[3] = f2bf(x.w);
        w[4] = f2bf(y.x); w[5] = f2bf(y.y); w[6] = f2bf(y.z); w[7] = f2bf(y.w);
        const int ch = (c0 >> 3) + jj;
        *(u16x8*)&Kl[b][rl][(ch ^ (rl & 7)) << 3] = w;
      }
    }
    {
      const int cc = tid & 63;
      const int r0 = (tid >> 6) << 4;
      const float* src = Vh + ((size_t)(t * 64 + r0)) * 64 + cc;
      for (int jj = 0; jj < 2; ++jj) {
        u16x8 w;
        for (int i = 0; i < 8; ++i) w[i] = f2bf(src[(size_t)(jj * 8 + i) * 64]);
        const int ch = (r0 >> 3) + jj;
        *(u16x8*)&Vt[b][cc][(ch ^ (cc & 7)) << 3] = w;
      }
    }
  };
  auto COMPUTE = [&](int b, bool diag) {
    f32x4 s[4] = {{0,0,0,0},{0,0,0,0},{0,0,0,0},{0,0,0,0}};
    for (int nt = 0; nt < 4; ++nt) {
      const ushort_t* row = &Kl[b][nt * 16 + col][0];
      const bf16x8 kf0 = *(const bf16x8*)(row + ch0);
      const bf16x8 kf1 = *(const bf16x8*)(row + ch1);
      s[nt] = __builtin_amdgcn_mfma_f32_16x16x32_bf16(kf0, qf[0], s[nt], 0, 0, 0);
      s[nt] = __builtin_amdgcn_mfma_f32_16x16x32_bf16(kf1, qf[1], s[nt], 0, 0, 0);
    }
    if (diag) {
      const int qloc = wave * 16 + col;
      for (int nt = 0; nt < 4; ++nt) {
        const int tb = 32 * (nt >> 1) + 4 * (nt & 1) + 8 * g;
        for (int r = 0; r < 4; ++r)
          if (tb + r > qloc) s[nt][r] = -INFINITY;
      }
    }
    float pm = -INFINITY;
    for (int nt = 0; nt < 4; ++nt)
      for (int r = 0; r < 4; ++r) pm = fmaxf(pm, s[nt][r]);
    pm = fmaxf(pm, __shfl_xor(pm, 16));
    pm = fmaxf(pm, __shfl_xor(pm, 32));
    float fac = 1.0f;
    if (!__all(pm - m_ <= 8.0f)) {
      const float mn = fmaxf(m_, pm);
      fac = fast_exp2(m_ - mn);
      m_ = mn;
      for (int nt = 0; nt < 4; ++nt) acc[nt] *= fac;
    }
    float sum = 0.0f;
    for (int nt = 0; nt < 4; ++nt)
      for (int r = 0; r < 4; ++r) {
        const float p = fast_exp2(s[nt][r] - m_);
        s[nt][r] = p;
        sum += p;
      }
    l_ = l_ * fac + sum;
    u32x4 t0, t1;
    t0[0] = cvt_pk_bf16(s[0][0], s[0][1]); t0[1] = cvt_pk_bf16(s[0][2], s[0][3]);
    t0[2] = cvt_pk_bf16(s[1][0], s[1][1]); t0[3] = cvt_pk_bf16(s[1][2], s[1][3]);
    t1[0] = cvt_pk_bf16(s[2][0], s[2][1]); t1[1] = cvt_pk_bf16(s[2][2], s[2][3]);
    t1[2] = cvt_pk_bf16(s[3][0], s[3][1]); t1[3] = cvt_pk_bf16(s[3][2], s[3][3]);
    const bf16x8 pf0 = __builtin_bit_cast(bf16x8, t0);
    const bf16x8 pf1 = __builtin_bit_cast(bf16x8, t1);
    for (int nt = 0; nt < 4; ++nt) {
      const ushort_t* row = &Vt[b][nt * 16 + col][0];
      const bf16x8 vf0 = *(const bf16x8*)(row + ch0);
      const bf16x8 vf1 = *(const bf16x8*)(row + ch1);
      acc[nt] = __builtin_amdgcn_mfma_f32_16x16x32_bf16(vf0, pf0, acc[nt], 0, 0, 0);
      acc[nt] = __builtin_amdgcn_mfma_f32_16x16x32_bf16(vf1, pf1, acc[nt], 0, 0, 0);
    }
  };
  int cur = 0;
  STAGE(0, 0);
  __syncthreads();
  for (int t = 0; t <= qt; ++t) {
    if (t < qt) STAGE(t + 1, cur ^ 1);
    COMPUTE(cur, t == qt);
    __syncthreads();
    cur ^= 1;
  }
  float lsum = l_;
  lsum += __shfl_xor(lsum, 16);
  lsum += __shfl_xor(lsum, 32);
  const float inv = 1.0f / lsum;
  float* dst = O + (size_t)bh * S_ * D_ + (size_t)qrow * 64;
  for (int nt = 0; nt < 4; ++nt) {
    f32x4 v = acc[nt];
    v *= inv;
    *(f32x4*)(dst + nt * 16 + 4 * g) = v;
  }
}

extern "C" void kernel_launch(void* const* d_in, const int* in_sizes, int n_in,
                              void* d_out, int out_size, void* d_ws, size_t ws_size,
                              hipStream_t stream) {
  const float* Q = (const float*)d_in[0];
  const float* K = (const float*)d_in[1];
  const float* V = (const float*)d_in[2];
  float* O = (float*)d_out;
  const size_t NE = (size_t)B_ * H_ * S_ * D_;            // 4194304
  const size_t needK = 2 * NE * sizeof(ushort_t);         // 16777216
  const size_t PO_elems = 32ull * 16 * 2 * 4096;
  const size_t ML_elems = 32ull * 16 * 2 * 128;
  const size_t needSplit = needK + (PO_elems + ML_elems) * sizeof(float);
  if (ws_size >= needSplit) {
    ushort_t* kg = (ushort_t*)d_ws;
    float* PO = (float*)((char*)d_ws + needK);
    float* ML = PO + PO_elems;
    prepack32<<<2048, 256, 0, stream>>>(K, V, kg, kg + NE);
    attn_s32<<<dim3(32, 48), 256, 0, stream>>>(Q, kg, kg + NE, O, PO, ML);
    merge_partials<<<dim3(32, 16), 256, 0, stream>>>(PO, ML, O);
  } else {
    attn_fb<<<dim3(32, 32), 256, 0, stream>>>(Q, K, V, O);
  }
}